// Round 3
// baseline (146.960 us; speedup 1.0000x reference)
//
#include <hip/hip_runtime.h>

// ContrastiveLoss: loss = sum_n [ log(sum_j exp(2*<ne_n,ne_j>)) - 2*<ne_n,nt_n> ] / (2N)
// N=8192, D=512.
// R2: compacted triangular grid (2080 blocks, exact fp32 tri-decode) +
//     double-buffered global_load_lds prefetch (1 barrier/iter, DMA latency
//     overlapped with MFMA). Fragment/epilogue code unchanged from verified R1.

typedef __attribute__((ext_vector_type(8))) short short8;
typedef __attribute__((ext_vector_type(4))) float floatx4;

#define N 8192
#define D 512
#define BK 32            // k-step in bf16 elems
#define NIT (D / BK)     // 16 k-iterations
#define NT 64            // 128-row tiles per dim

__device__ __forceinline__ unsigned short f2bf(float f) {
    unsigned int u = __float_as_uint(f);
    unsigned int r = u + 0x7fffu + ((u >> 16) & 1u);   // round-to-nearest-even
    return (unsigned short)(r >> 16);
}

__device__ __forceinline__ void gload_lds16(const void* g, void* l) {
    __builtin_amdgcn_global_load_lds(
        (const __attribute__((address_space(1))) void*)g,
        (__attribute__((address_space(3))) void*)l, 16, 0, 0);
}

__global__ __launch_bounds__(256) void k_norm(const float* __restrict__ emb,
                                              const float* __restrict__ tgt,
                                              unsigned short* __restrict__ neb,
                                              float* __restrict__ pos,
                                              float* __restrict__ out) {
    if (blockIdx.x == 0 && threadIdx.x == 0) *out = 0.0f;   // replaces memset dispatch
    int wave = threadIdx.x >> 6;
    int lane = threadIdx.x & 63;
    int row  = blockIdx.x * 4 + wave;          // one wave per row
    const float4* e4 = (const float4*)(emb + (size_t)row * D) + lane * 2;
    const float4* t4 = (const float4*)(tgt + (size_t)row * D) + lane * 2;
    float4 e0 = e4[0], e1 = e4[1];
    float4 t0 = t4[0], t1 = t4[1];
    float ee = e0.x*e0.x + e0.y*e0.y + e0.z*e0.z + e0.w*e0.w
             + e1.x*e1.x + e1.y*e1.y + e1.z*e1.z + e1.w*e1.w;
    float tt = t0.x*t0.x + t0.y*t0.y + t0.z*t0.z + t0.w*t0.w
             + t1.x*t1.x + t1.y*t1.y + t1.z*t1.z + t1.w*t1.w;
    float et = e0.x*t0.x + e0.y*t0.y + e0.z*t0.z + e0.w*t0.w
             + e1.x*t1.x + e1.y*t1.y + e1.z*t1.z + e1.w*t1.w;
    #pragma unroll
    for (int off = 1; off < 64; off <<= 1) {
        ee += __shfl_xor(ee, off);
        tt += __shfl_xor(tt, off);
        et += __shfl_xor(et, off);
    }
    float se = fmaxf(sqrtf(ee), 1e-12f);
    float st = fmaxf(sqrtf(tt), 1e-12f);
    if (lane == 0) pos[row] = et / (se * st);
    float inv = 1.0f / se;
    unsigned short v0 = f2bf(e0.x*inv), v1 = f2bf(e0.y*inv), v2 = f2bf(e0.z*inv), v3 = f2bf(e0.w*inv);
    unsigned short v4 = f2bf(e1.x*inv), v5 = f2bf(e1.y*inv), v6 = f2bf(e1.z*inv), v7 = f2bf(e1.w*inv);
    uint4 pk;
    pk.x = (unsigned)v0 | ((unsigned)v1 << 16);
    pk.y = (unsigned)v2 | ((unsigned)v3 << 16);
    pk.z = (unsigned)v4 | ((unsigned)v5 << 16);
    pk.w = (unsigned)v6 | ((unsigned)v7 << 16);
    ((uint4*)(neb + (size_t)row * D))[lane] = pk;
}

// LDS: 2 x [128][BK] bf16 per operand (32 KB total). 16B chunk (row,c) at
// slot row*4 + (c ^ (row&3)): lane-linear slots for global_load_lds staging.
__global__ __launch_bounds__(256) void k_gemm(const unsigned short* __restrict__ neb,
                                              float* __restrict__ partial) {
    __shared__ unsigned short sA[2][128 * BK];
    __shared__ unsigned short sB[2][128 * BK];

    // exact triangular decode: t -> (bi, bj), bi <= bj, row-major upper tri
    const int t = blockIdx.x;
    int bi = (int)((129.0f - sqrtf(16641.0f - 8.0f * (float)t)) * 0.5f);
    int start = bi * (129 - bi) / 2;
    if (t < start)                        { --bi; start = bi * (129 - bi) / 2; }
    else { int s1 = (bi + 1) * (128 - bi) / 2; if (t >= s1) { ++bi; start = s1; } }
    const int bj = bi + (t - start);

    const int tid  = threadIdx.x;
    const int i0   = bi * 128, j0 = bj * 128;
    const int wave = tid >> 6, lane = tid & 63;
    const int wrow = wave >> 1, wcol = wave & 1;   // 2x2 waves, each 64x64
    const int m16  = lane & 15, quad = lane >> 4;
    const int swz  = quad ^ (m16 & 3);             // lane-constant read swizzle

    // staging: wave w covers LDS chunk-slots [w*128, w*128+128), lane-linear
    const int slot0 = wave * 128 + lane;
    const int slot1 = slot0 + 64;
    const int r0 = slot0 >> 2, cc0 = (slot0 & 3) ^ (r0 & 3);
    const int r1 = slot1 >> 2, cc1 = (slot1 & 3) ^ (r1 & 3);
    const unsigned short* gA0 = neb + (size_t)(i0 + r0) * D + cc0 * 8;
    const unsigned short* gA1 = neb + (size_t)(i0 + r1) * D + cc1 * 8;
    const unsigned short* gB0 = neb + (size_t)(j0 + r0) * D + cc0 * 8;
    const unsigned short* gB1 = neb + (size_t)(j0 + r1) * D + cc1 * 8;
    const int ldo0 = (wave * 128) * 8;        // element offset of this wave's slots
    const int ldo1 = (wave * 128 + 64) * 8;

    floatx4 zero = {0.f, 0.f, 0.f, 0.f};
    floatx4 acc[4][4];
    #pragma unroll
    for (int a = 0; a < 4; ++a)
        #pragma unroll
        for (int b = 0; b < 4; ++b) acc[a][b] = zero;

    // prologue: stage k-chunk 0 into buffer 0
    gload_lds16(gA0, &sA[0][ldo0]);
    gload_lds16(gA1, &sA[0][ldo1]);
    gload_lds16(gB0, &sB[0][ldo0]);
    gload_lds16(gB1, &sB[0][ldo1]);

    for (int it = 0; it < NIT; ++it) {
        __syncthreads();                       // drains DMA for buffer it&1
        if (it + 1 < NIT) {                    // prefetch next chunk into alt buffer
            const int kt = (it + 1) * BK;
            const int b  = (it + 1) & 1;
            gload_lds16(gA0 + kt, &sA[b][ldo0]);
            gload_lds16(gA1 + kt, &sA[b][ldo1]);
            gload_lds16(gB0 + kt, &sB[b][ldo0]);
            gload_lds16(gB1 + kt, &sB[b][ldo1]);
        }
        const unsigned short* cA = sA[it & 1];
        const unsigned short* cB = sB[it & 1];
        short8 af[4], bfr[4];
        #pragma unroll
        for (int tt2 = 0; tt2 < 4; ++tt2) {
            af[tt2]  = *(const short8*)(&cA[(wrow * 64 + tt2 * 16 + m16) * BK + swz * 8]);
            bfr[tt2] = *(const short8*)(&cB[(wcol * 64 + tt2 * 16 + m16) * BK + swz * 8]);
        }
        #pragma unroll
        for (int ti = 0; ti < 4; ++ti)
            #pragma unroll
            for (int tj = 0; tj < 4; ++tj)
                acc[ti][tj] = __builtin_amdgcn_mfma_f32_16x16x32_bf16(af[ti], bfr[tj], acc[ti][tj], 0, 0, 0);
    }

    // row-sums: exp(2*c) summed over this block's 128 cols -> slot bj*2+wcol
    const int prow = bj * 2 + wcol;
    #pragma unroll
    for (int ti = 0; ti < 4; ++ti) {
        #pragma unroll
        for (int r = 0; r < 4; ++r) {
            float s = 0.f;
            #pragma unroll
            for (int tj = 0; tj < 4; ++tj) s += __expf(2.0f * acc[ti][tj][r]);
            #pragma unroll
            for (int off = 1; off < 16; off <<= 1) s += __shfl_xor(s, off);
            if (m16 == 0) {
                int rowg = i0 + wrow * 64 + ti * 16 + quad * 4 + r;
                partial[(size_t)prow * N + rowg] = s;
            }
        }
    }
    // col-sums (symmetry: = row-sums of skipped tile (bj,bi)) -> slot bi*2+wrow
    if (bi < bj) {
        const int pcol = bi * 2 + wrow;
        #pragma unroll
        for (int tj = 0; tj < 4; ++tj) {
            float s = 0.f;
            #pragma unroll
            for (int ti = 0; ti < 4; ++ti) {
                #pragma unroll
                for (int r = 0; r < 4; ++r) s += __expf(2.0f * acc[ti][tj][r]);
            }
            s += __shfl_xor(s, 16);
            s += __shfl_xor(s, 32);
            if (quad == 0) {
                int colg = j0 + wcol * 64 + tj * 16 + m16;
                partial[(size_t)pcol * N + colg] = s;
            }
        }
    }
}

__global__ __launch_bounds__(256) void k_final(const float* __restrict__ partial,
                                               const float* __restrict__ pos,
                                               float* __restrict__ out) {
    int tid = threadIdx.x;
    int row = blockIdx.x * 64 + (tid >> 2);
    int sub = tid & 3;
    float S = 0.f;
    #pragma unroll
    for (int i = 0; i < 32; ++i) S += partial[(size_t)(sub + i * 4) * N + row];
    S += __shfl_xor(S, 1);
    S += __shfl_xor(S, 2);
    float val = (sub == 0) ? (logf(S) - 2.0f * pos[row]) : 0.0f;
    #pragma unroll
    for (int off = 4; off < 64; off <<= 1) val += __shfl_xor(val, off);
    if ((tid & 63) == 0) atomicAdd(out, val * (1.0f / (2.0f * N)));
}

extern "C" void kernel_launch(void* const* d_in, const int* in_sizes, int n_in,
                              void* d_out, int out_size, void* d_ws, size_t ws_size,
                              hipStream_t stream) {
    const float* emb = (const float*)d_in[0];
    const float* tgt = (const float*)d_in[1];
    unsigned short* neb = (unsigned short*)d_ws;                                 // 8 MB bf16 ne
    float* pos     = (float*)((char*)d_ws + (size_t)N * D * 2);                  // 32 KB
    float* partial = (float*)((char*)d_ws + (size_t)N * D * 2 + (size_t)N * 4);  // 4 MB
    float* out = (float*)d_out;

    k_norm<<<N / 4, 256, 0, stream>>>(emb, tgt, neb, pos, out);
    k_gemm<<<NT * (NT + 1) / 2, 256, 0, stream>>>(neb, partial);
    k_final<<<N / 64, 256, 0, stream>>>(partial, pos, out);
}

// Round 4
// 140.031 us; speedup vs baseline: 1.0495x; 1.0495x over previous
//
#include <hip/hip_runtime.h>

// ContrastiveLoss: loss = sum_n [ log(sum_j exp(2*<ne_n,ne_j>)) - 2*<ne_n,nt_n> ] / (2N)
// N=8192, D=512.
// R3: XCD-partitioned schedule. Triangle of 64x64 tiles grouped into 8x8
//     supertiles; the 36 supertile-pairs are statically assigned to XCDs
//     (blockIdx%8 ~ XCD round-robin) so each XCD's resident blocks read a
//     2-4 MB strip set that fits its private 4 MB L2. Each XCD stream:
//     1 diag pair (36 blocks) + 3 off-diag pairs (64 each) + half of a
//     split pair (32) = 260 blocks; 8*260 = 2080 = full triangle.
//     Compute path (dbuf DMA staging, fragments, epilogue) identical to R2.

typedef __attribute__((ext_vector_type(8))) short short8;
typedef __attribute__((ext_vector_type(4))) float floatx4;

#define N 8192
#define D 512
#define BK 32            // k-step in bf16 elems
#define NIT (D / BK)     // 16 k-iterations
#define NT 64            // 128-row tiles per dim

__device__ __forceinline__ unsigned short f2bf(float f) {
    unsigned int u = __float_as_uint(f);
    unsigned int r = u + 0x7fffu + ((u >> 16) & 1u);   // round-to-nearest-even
    return (unsigned short)(r >> 16);
}

__device__ __forceinline__ void gload_lds16(const void* g, void* l) {
    __builtin_amdgcn_global_load_lds(
        (const __attribute__((address_space(1))) void*)g,
        (__attribute__((address_space(3))) void*)l, 16, 0, 0);
}

// Per-XCD segment tables: 5 segments each = [diag36, off64, off64, off64, half32].
// Coverage (verified by enumeration): diag (g,g) for g=0..7 once each;
// off-diag pairs all 28 once each, with (0,1),(2,3),(4,5),(6,7) split half/half
// between their two owner XCDs (odd XCD takes the upper half).
__device__ __constant__ unsigned char seg_ga[8][5] = {
    {0,0,0,0,0},{1,1,1,1,0},{2,2,2,2,2},{3,3,3,3,2},
    {4,0,0,0,4},{5,1,1,1,4},{6,2,3,4,6},{7,4,5,5,6}};
__device__ __constant__ unsigned char seg_gb[8][5] = {
    {0,2,3,4,1},{1,2,3,4,1},{2,5,6,7,3},{3,5,6,7,3},
    {4,5,6,7,5},{5,5,6,7,5},{6,4,4,6,7},{7,7,6,7,7}};

__global__ __launch_bounds__(256) void k_norm(const float* __restrict__ emb,
                                              const float* __restrict__ tgt,
                                              unsigned short* __restrict__ neb,
                                              float* __restrict__ pos,
                                              float* __restrict__ out) {
    if (blockIdx.x == 0 && threadIdx.x == 0) *out = 0.0f;   // replaces memset dispatch
    int wave = threadIdx.x >> 6;
    int lane = threadIdx.x & 63;
    int row  = blockIdx.x * 4 + wave;          // one wave per row
    const float4* e4 = (const float4*)(emb + (size_t)row * D) + lane * 2;
    const float4* t4 = (const float4*)(tgt + (size_t)row * D) + lane * 2;
    float4 e0 = e4[0], e1 = e4[1];
    float4 t0 = t4[0], t1 = t4[1];
    float ee = e0.x*e0.x + e0.y*e0.y + e0.z*e0.z + e0.w*e0.w
             + e1.x*e1.x + e1.y*e1.y + e1.z*e1.z + e1.w*e1.w;
    float tt = t0.x*t0.x + t0.y*t0.y + t0.z*t0.z + t0.w*t0.w
             + t1.x*t1.x + t1.y*t1.y + t1.z*t1.z + t1.w*t1.w;
    float et = e0.x*t0.x + e0.y*t0.y + e0.z*t0.z + e0.w*t0.w
             + e1.x*t1.x + e1.y*t1.y + e1.z*t1.z + e1.w*t1.w;
    #pragma unroll
    for (int off = 1; off < 64; off <<= 1) {
        ee += __shfl_xor(ee, off);
        tt += __shfl_xor(tt, off);
        et += __shfl_xor(et, off);
    }
    float se = fmaxf(sqrtf(ee), 1e-12f);
    float st = fmaxf(sqrtf(tt), 1e-12f);
    if (lane == 0) pos[row] = et / (se * st);
    float inv = 1.0f / se;
    unsigned short v0 = f2bf(e0.x*inv), v1 = f2bf(e0.y*inv), v2 = f2bf(e0.z*inv), v3 = f2bf(e0.w*inv);
    unsigned short v4 = f2bf(e1.x*inv), v5 = f2bf(e1.y*inv), v6 = f2bf(e1.z*inv), v7 = f2bf(e1.w*inv);
    uint4 pk;
    pk.x = (unsigned)v0 | ((unsigned)v1 << 16);
    pk.y = (unsigned)v2 | ((unsigned)v3 << 16);
    pk.z = (unsigned)v4 | ((unsigned)v5 << 16);
    pk.w = (unsigned)v6 | ((unsigned)v7 << 16);
    ((uint4*)(neb + (size_t)row * D))[lane] = pk;
}

// LDS: 2 x [128][BK] bf16 per operand (32 KB total). 16B chunk (row,c) at
// slot row*4 + (c ^ (row&3)): lane-linear slots for global_load_lds staging.
__global__ __launch_bounds__(256) void k_gemm(const unsigned short* __restrict__ neb,
                                              float* __restrict__ partial) {
    __shared__ unsigned short sA[2][128 * BK];
    __shared__ unsigned short sB[2][128 * BK];

    // XCD-partitioned decode: x = XCD stream, s = sequence within stream
    const int x = (int)(blockIdx.x & 7);
    int s = (int)(blockIdx.x >> 3);          // 0..259
    int seg, u;
    if (s < 36)       { seg = 0; u = s; }
    else if (s < 100) { seg = 1; u = s - 36; }
    else if (s < 164) { seg = 2; u = s - 100; }
    else if (s < 228) { seg = 3; u = s - 164; }
    else              { seg = 4; u = s - 228 + ((x & 1) ? 32 : 0); }
    const int ga = seg_ga[x][seg], gb = seg_gb[x][seg];
    int bi, bj;
    if (seg == 0) {                           // diag supertile: tri decode in 8x8
        int di = 0;
        while (u >= 8 - di) { u -= 8 - di; ++di; }
        bi = ga * 8 + di; bj = gb * 8 + di + u;
    } else {
        bi = ga * 8 + (u >> 3); bj = gb * 8 + (u & 7);
    }

    const int tid  = threadIdx.x;
    const int i0   = bi * 128, j0 = bj * 128;
    const int wave = tid >> 6, lane = tid & 63;
    const int wrow = wave >> 1, wcol = wave & 1;   // 2x2 waves, each 64x64
    const int m16  = lane & 15, quad = lane >> 4;
    const int swz  = quad ^ (m16 & 3);             // lane-constant read swizzle

    // staging: wave w covers LDS chunk-slots [w*128, w*128+128), lane-linear
    const int slot0 = wave * 128 + lane;
    const int slot1 = slot0 + 64;
    const int r0 = slot0 >> 2, cc0 = (slot0 & 3) ^ (r0 & 3);
    const int r1 = slot1 >> 2, cc1 = (slot1 & 3) ^ (r1 & 3);
    const unsigned short* gA0 = neb + (size_t)(i0 + r0) * D + cc0 * 8;
    const unsigned short* gA1 = neb + (size_t)(i0 + r1) * D + cc1 * 8;
    const unsigned short* gB0 = neb + (size_t)(j0 + r0) * D + cc0 * 8;
    const unsigned short* gB1 = neb + (size_t)(j0 + r1) * D + cc1 * 8;
    const int ldo0 = (wave * 128) * 8;        // element offset of this wave's slots
    const int ldo1 = (wave * 128 + 64) * 8;

    floatx4 zero = {0.f, 0.f, 0.f, 0.f};
    floatx4 acc[4][4];
    #pragma unroll
    for (int a = 0; a < 4; ++a)
        #pragma unroll
        for (int b = 0; b < 4; ++b) acc[a][b] = zero;

    // prologue: stage k-chunk 0 into buffer 0
    gload_lds16(gA0, &sA[0][ldo0]);
    gload_lds16(gA1, &sA[0][ldo1]);
    gload_lds16(gB0, &sB[0][ldo0]);
    gload_lds16(gB1, &sB[0][ldo1]);

    for (int it = 0; it < NIT; ++it) {
        __syncthreads();                       // drains DMA for buffer it&1
        if (it + 1 < NIT) {                    // prefetch next chunk into alt buffer
            const int kt = (it + 1) * BK;
            const int b  = (it + 1) & 1;
            gload_lds16(gA0 + kt, &sA[b][ldo0]);
            gload_lds16(gA1 + kt, &sA[b][ldo1]);
            gload_lds16(gB0 + kt, &sB[b][ldo0]);
            gload_lds16(gB1 + kt, &sB[b][ldo1]);
        }
        const unsigned short* cA = sA[it & 1];
        const unsigned short* cB = sB[it & 1];
        short8 af[4], bfr[4];
        #pragma unroll
        for (int tt2 = 0; tt2 < 4; ++tt2) {
            af[tt2]  = *(const short8*)(&cA[(wrow * 64 + tt2 * 16 + m16) * BK + swz * 8]);
            bfr[tt2] = *(const short8*)(&cB[(wcol * 64 + tt2 * 16 + m16) * BK + swz * 8]);
        }
        #pragma unroll
        for (int ti = 0; ti < 4; ++ti)
            #pragma unroll
            for (int tj = 0; tj < 4; ++tj)
                acc[ti][tj] = __builtin_amdgcn_mfma_f32_16x16x32_bf16(af[ti], bfr[tj], acc[ti][tj], 0, 0, 0);
    }

    // row-sums: exp(2*c) summed over this block's 128 cols -> slot bj*2+wcol
    const int prow = bj * 2 + wcol;
    #pragma unroll
    for (int ti = 0; ti < 4; ++ti) {
        #pragma unroll
        for (int r = 0; r < 4; ++r) {
            float ss = 0.f;
            #pragma unroll
            for (int tj = 0; tj < 4; ++tj) ss += __expf(2.0f * acc[ti][tj][r]);
            #pragma unroll
            for (int off = 1; off < 16; off <<= 1) ss += __shfl_xor(ss, off);
            if (m16 == 0) {
                int rowg = i0 + wrow * 64 + ti * 16 + quad * 4 + r;
                partial[(size_t)prow * N + rowg] = ss;
            }
        }
    }
    // col-sums (symmetry: = row-sums of skipped tile (bj,bi)) -> slot bi*2+wrow
    if (bi < bj) {
        const int pcol = bi * 2 + wrow;
        #pragma unroll
        for (int tj = 0; tj < 4; ++tj) {
            float ss = 0.f;
            #pragma unroll
            for (int ti = 0; ti < 4; ++ti) {
                #pragma unroll
                for (int r = 0; r < 4; ++r) ss += __expf(2.0f * acc[ti][tj][r]);
            }
            ss += __shfl_xor(ss, 16);
            ss += __shfl_xor(ss, 32);
            if (quad == 0) {
                int colg = j0 + wcol * 64 + tj * 16 + m16;
                partial[(size_t)pcol * N + colg] = ss;
            }
        }
    }
}

__global__ __launch_bounds__(256) void k_final(const float* __restrict__ partial,
                                               const float* __restrict__ pos,
                                               float* __restrict__ out) {
    int tid = threadIdx.x;
    int row = blockIdx.x * 64 + (tid >> 2);
    int sub = tid & 3;
    float S = 0.f;
    #pragma unroll
    for (int i = 0; i < 32; ++i) S += partial[(size_t)(sub + i * 4) * N + row];
    S += __shfl_xor(S, 1);
    S += __shfl_xor(S, 2);
    float val = (sub == 0) ? (logf(S) - 2.0f * pos[row]) : 0.0f;
    #pragma unroll
    for (int off = 4; off < 64; off <<= 1) val += __shfl_xor(val, off);
    if ((tid & 63) == 0) atomicAdd(out, val * (1.0f / (2.0f * N)));
}

extern "C" void kernel_launch(void* const* d_in, const int* in_sizes, int n_in,
                              void* d_out, int out_size, void* d_ws, size_t ws_size,
                              hipStream_t stream) {
    const float* emb = (const float*)d_in[0];
    const float* tgt = (const float*)d_in[1];
    unsigned short* neb = (unsigned short*)d_ws;                                 // 8 MB bf16 ne
    float* pos     = (float*)((char*)d_ws + (size_t)N * D * 2);                  // 32 KB
    float* partial = (float*)((char*)d_ws + (size_t)N * D * 2 + (size_t)N * 4);  // 4 MB
    float* out = (float*)d_out;

    k_norm<<<N / 4, 256, 0, stream>>>(emb, tgt, neb, pos, out);
    k_gemm<<<NT * (NT + 1) / 2, 256, 0, stream>>>(neb, partial);
    k_final<<<N / 64, 256, 0, stream>>>(partial, pos, out);
}